// Round 1
// baseline (4243.969 us; speedup 1.0000x reference)
//
#include <hip/hip_runtime.h>

// Circular depthwise 7x7 conv, NHWC, fp32.
// out[b,h,w,c] = sum_{i,j} K[c,i,j] * x[b,(h+3-i)%H,(w+3-j)%W,c]

#define Bn 8
#define Hn 224
#define Wn 224
#define Cn 192
#define Kn 7
#define TW 28          // output columns per thread
#define TH 4           // output rows per block
#define C4 (Cn/4)      // 48 float4 channel groups

// Transpose (C,7,7) weights -> wT[(i*7+j)*C + c] so channel dim is contiguous.
__global__ void transpose_weights(const float* __restrict__ k, float* __restrict__ wT) {
    int o = blockIdx.x * 256 + threadIdx.x;
    if (o < Cn * Kn * Kn) {
        int c = o % Cn;
        int r = o / Cn;              // r = i*7 + j
        wT[o] = k[c * (Kn * Kn) + r];
    }
}

__global__ __launch_bounds__(192, 3)
void dwconv7x7(const float4* __restrict__ x, const float4* __restrict__ wT,
               float4* __restrict__ out) {
    const int tx = threadIdx.x;               // 0..47 channel group
    const int ty = threadIdx.y;               // 0..3 row within tile
    const int w0 = blockIdx.x * TW;
    const int h  = blockIdx.y * TH + ty;
    const int b  = blockIdx.z;

    float4 acc[TW];
#pragma unroll
    for (int t = 0; t < TW; ++t) acc[t] = make_float4(0.f, 0.f, 0.f, 0.f);

    for (int i = 0; i < Kn; ++i) {
        int row = h + 3 - i;
        row += (row < 0)   ? Hn : 0;
        row -= (row >= Hn) ? Hn : 0;
        const float4* __restrict__ xrow = x + (size_t)(b * Hn + row) * (Wn * C4) + tx;

        float4 wv[Kn];
#pragma unroll
        for (int j = 0; j < Kn; ++j) wv[j] = wT[(i * Kn + j) * C4 + tx];

#pragma unroll
        for (int u = 0; u < TW + 6; ++u) {
            int col = w0 + u - 3;
            col += (col < 0)   ? Wn : 0;
            col -= (col >= Wn) ? Wn : 0;
            float4 xv = xrow[col * C4];
#pragma unroll
            for (int j = 0; j < Kn; ++j) {
                int tw = u + j - 6;              // compile-time after unroll
                if (tw >= 0 && tw < TW) {
                    acc[tw].x += wv[j].x * xv.x;
                    acc[tw].y += wv[j].y * xv.y;
                    acc[tw].z += wv[j].z * xv.z;
                    acc[tw].w += wv[j].w * xv.w;
                }
            }
        }
    }

    float4* __restrict__ orow = out + (size_t)(b * Hn + h) * (Wn * C4) + tx;
#pragma unroll
    for (int t = 0; t < TW; ++t) orow[(w0 + t) * C4] = acc[t];
}

extern "C" void kernel_launch(void* const* d_in, const int* in_sizes, int n_in,
                              void* d_out, int out_size, void* d_ws, size_t ws_size,
                              hipStream_t stream) {
    const float* x = (const float*)d_in[0];          // (8,224,224,192) fp32
    const float* k = (const float*)d_in[1];          // (192,7,7) fp32
    float* wT = (float*)d_ws;                        // 9408 floats scratch

    int nW = Cn * Kn * Kn;
    transpose_weights<<<(nW + 255) / 256, 256, 0, stream>>>(k, wT);

    dim3 grid(Wn / TW, Hn / TH, Bn);                 // (8, 56, 8)
    dim3 block(C4, TH, 1);                           // (48, 4) = 192 threads
    dwconv7x7<<<grid, block, 0, stream>>>((const float4*)x, (const float4*)wT,
                                          (float4*)d_out);
}

// Round 2
// 653.561 us; speedup vs baseline: 6.4936x; 6.4936x over previous
//
#include <hip/hip_runtime.h>

// Circular depthwise 7x7 conv, NHWC, fp32.
// out[b,h,w,c] = sum_{i,j} K[c,i,j] * x[b,(h+3-i)%H,(w+3-j)%W,c]

#define Bn 8
#define Hn 224
#define Wn 224
#define Cn 192
#define Kn 7
#define TW 16          // output columns per thread (64 acc VGPRs)
#define TH 4           // output rows per block
#define C4 (Cn/4)      // 48 float4 channel groups

// Transpose (C,7,7) weights -> wT[(i*7+j)*C + c] so channel dim is contiguous.
__global__ void transpose_weights(const float* __restrict__ k, float* __restrict__ wT) {
    int o = blockIdx.x * 256 + threadIdx.x;
    if (o < Cn * Kn * Kn) {
        int c = o % Cn;
        int r = o / Cn;              // r = i*7 + j
        wT[o] = k[c * (Kn * Kn) + r];
    }
}

__global__ __launch_bounds__(192, 2)
void dwconv7x7(const float4* __restrict__ x, const float4* __restrict__ wT,
               float4* __restrict__ out) {
    const int tx = threadIdx.x;               // 0..47 channel group
    const int ty = threadIdx.y;               // 0..3 row within tile
    const int w0 = blockIdx.x * TW;
    const int h  = blockIdx.y * TH + ty;
    const int b  = blockIdx.z;

    float4 acc[TW];
#pragma unroll
    for (int t = 0; t < TW; ++t) acc[t] = make_float4(0.f, 0.f, 0.f, 0.f);

    for (int i = 0; i < Kn; ++i) {
        int row = h + 3 - i;
        row += (row < 0)   ? Hn : 0;
        row -= (row >= Hn) ? Hn : 0;
        const float4* __restrict__ xrow = x + (size_t)(b * Hn + row) * (Wn * C4) + tx;

        float4 wv[Kn];
#pragma unroll
        for (int j = 0; j < Kn; ++j) wv[j] = wT[(i * Kn + j) * C4 + tx];

#pragma unroll
        for (int u = 0; u < TW + 6; ++u) {
            int col = w0 + u - 3;
            col += (col < 0)   ? Wn : 0;
            col -= (col >= Wn) ? Wn : 0;
            float4 xv = xrow[col * C4];
#pragma unroll
            for (int j = 0; j < Kn; ++j) {
                int tw = u + j - 6;              // compile-time after unroll
                if (tw >= 0 && tw < TW) {
                    acc[tw].x += wv[j].x * xv.x;
                    acc[tw].y += wv[j].y * xv.y;
                    acc[tw].z += wv[j].z * xv.z;
                    acc[tw].w += wv[j].w * xv.w;
                }
            }
        }
    }

    float4* __restrict__ orow = out + (size_t)(b * Hn + h) * (Wn * C4) + tx;
#pragma unroll
    for (int t = 0; t < TW; ++t) orow[(w0 + t) * C4] = acc[t];
}

extern "C" void kernel_launch(void* const* d_in, const int* in_sizes, int n_in,
                              void* d_out, int out_size, void* d_ws, size_t ws_size,
                              hipStream_t stream) {
    const float* x = (const float*)d_in[0];          // (8,224,224,192) fp32
    const float* k = (const float*)d_in[1];          // (192,7,7) fp32
    float* wT = (float*)d_ws;                        // 9408 floats scratch

    int nW = Cn * Kn * Kn;
    transpose_weights<<<(nW + 255) / 256, 256, 0, stream>>>(k, wT);

    dim3 grid(Wn / TW, Hn / TH, Bn);                 // (14, 56, 8)
    dim3 block(C4, TH, 1);                           // (48, 4) = 192 threads
    dwconv7x7<<<grid, block, 0, stream>>>((const float4*)x, (const float4*)wT,
                                          (float4*)d_out);
}